// Round 17
// baseline (307.427 us; speedup 1.0000x reference)
//
#include <hip/hip_runtime.h>
#include <hip/hip_fp16.h>
#include <cstdint>

#define TABLE_MASK 0x3FFFFFu   // 2^22 - 1
#define P2 2654435761u
#define P3 805459861u

#define XD 128                  // exdx x-extent (record x = ix in [0,127])
#define YD 132                  // cy in [1,131]
#define ZD 132                  // cz in [1,131]
#define RECU 16                 // 16 uints = 64 B-aligned cell: Ex(6) + Dx(6) + pad(4, never touched)
#define NB3 (128 * 128 * 8)     // bins: (iz, iy, ix/16) raster = 131072
#define SCAN_BLKS (NB3 / 1024)  // 128
#define BUILD_BLKS (131 * 66)   // 8646

__device__ __forceinline__ float sigmoidf_(float x) { return 1.0f / (1.0f + expf(-x)); }

__device__ __forceinline__ uint32_t f2h2(float a, float b) {
    __half2 h = __floats2half2_rn(a, b);
    return *reinterpret_cast<uint32_t*>(&h);
}
__device__ __forceinline__ __half2 u2h2(uint32_t u) {
    return *reinterpret_cast<__half2*>(&u);
}

// ---------- sort key: raster (iz, iy, ix/16) ----------
__device__ __forceinline__ int bin_key3(float px, float py, float pz)
{
    float x = ((px + 10.0f) / 20.0f) * 128.0f;
    float y = ((py + 10.0f) / 20.0f) * 128.0f;
    float z = ((pz + 10.0f) / 20.0f) * 128.0f;
    int ix = min(max((int)floorf(x), 0), 127);
    int iy = min(max((int)floorf(y), 0), 127);
    int iz = min(max((int)floorf(z), 0), 127);
    return (((iz << 7) + iy) << 3) + (ix >> 4);
}

// ---------- fused prepass: build exdx volume (64 B-aligned records) + histogram ----------
__global__ __launch_bounds__(256)
void build_hist_kernel(const float4* __restrict__ gauss,
                       const float4* __restrict__ vmf,
                       uint32_t* __restrict__ exdx,
                       const float* __restrict__ pos,
                       uint32_t* __restrict__ hist, int n)
{
    if (blockIdx.x >= BUILD_BLKS) {
        int p = (blockIdx.x - BUILD_BLKS) * blockDim.x + threadIdx.x;
        if (p < n) {
            int k = bin_key3(pos[3 * p], pos[3 * p + 1], pos[3 * p + 2]);
            atomicAdd(&hist[k], 1u);
        }
        return;
    }

    __shared__ float sm[2][131][13];
    int bidx = blockIdx.x;              // 131 z * 66 y-pairs
    int yp = bidx % 66;
    int rz = 1 + bidx / 66;             // [1,131]
    int ry0 = 1 + 2 * yp;
    int t = threadIdx.x;

    for (int l = t; l < 262; l += 256) {
        int row = (l >= 131) ? 1 : 0;
        int cell = l - row * 131;
        int ry = ry0 + row;
        if (ry <= 131) {
            int xc = 1 + cell;
            uint32_t ux = (uint32_t)(xc - 2);
            uint32_t uy = (uint32_t)(ry - 2);
            uint32_t uz = (uint32_t)(rz - 2);
            uint32_t h = (ux ^ (uy * P2) ^ (uz * P3)) & TABLE_MASK;
            float4 g  = gauss[h];
            float4 v0 = vmf[(size_t)2 * h];
            float4 v1 = vmf[(size_t)2 * h + 1];
            float* s = sm[row][cell];
            s[0] = g.x;  s[1] = g.y;  s[2]  = g.z;  s[3]  = g.w;
            s[4] = v0.x; s[5] = v0.y; s[6]  = v0.z; s[7]  = v0.w;
            s[8] = v1.x; s[9] = v1.y; s[10] = v1.z; s[11] = v1.w;
        }
    }
    __syncthreads();

    int row = t >> 7;
    int c   = t & 127;
    int ry  = ry0 + row;
    if (ry > 131) return;

    uint32_t rec[12];
#pragma unroll
    for (int m = 0; m < 6; ++m) {
        float e0 = sm[row][c][2*m]   + sm[row][c+1][2*m]   + sm[row][c+2][2*m];
        float e1 = sm[row][c][2*m+1] + sm[row][c+1][2*m+1] + sm[row][c+2][2*m+1];
        float d0 = sm[row][c+3][2*m]   - sm[row][c][2*m];
        float d1 = sm[row][c+3][2*m+1] - sm[row][c][2*m+1];
        rec[m]     = f2h2(e0, e1);
        rec[6 + m] = f2h2(d0, d1);
    }
    size_t o = (((size_t)rz * YD + (size_t)ry) * XD + (size_t)c) * RECU;
    *(uint4*)(exdx + o)     = make_uint4(rec[0], rec[1], rec[2],  rec[3]);
    *(uint4*)(exdx + o + 4) = make_uint4(rec[4], rec[5], rec[6],  rec[7]);
    *(uint4*)(exdx + o + 8) = make_uint4(rec[8], rec[9], rec[10], rec[11]);
    // pad words [12..16) intentionally not written (never read)
}

// ---------- scanA: per-1024-chunk exclusive prefix + chunk sums ----------
__global__ __launch_bounds__(1024)
void scanA_kernel(const uint32_t* __restrict__ hist,
                  uint32_t* __restrict__ cursor,
                  uint32_t* __restrict__ sums)
{
    __shared__ uint32_t buf[1024];
    int t = threadIdx.x;
    int base = blockIdx.x * 1024;
    uint32_t v = hist[base + t];
    buf[t] = v;
    __syncthreads();
    for (int off = 1; off < 1024; off <<= 1) {
        uint32_t x = (t >= off) ? buf[t - off] : 0u;
        __syncthreads();
        buf[t] += x;
        __syncthreads();
    }
    cursor[base + t] = buf[t] - v;
    if (t == 1023) sums[blockIdx.x] = buf[t];
}

// ---------- scatter: redundant in-block scan of 128 chunk sums, then place ----------
__global__ __launch_bounds__(256)
void scatter_kernel(const float* __restrict__ pos,
                    uint32_t* __restrict__ cursor,
                    const uint32_t* __restrict__ sums,
                    float4* __restrict__ sortedPts, int n)
{
    __shared__ uint32_t soff[SCAN_BLKS];
    int t = threadIdx.x;
    if (t < SCAN_BLKS) soff[t] = sums[t];
    __syncthreads();
    for (int off = 1; off < SCAN_BLKS; off <<= 1) {
        uint32_t v = 0;
        if (t < SCAN_BLKS && t >= off) v = soff[t - off];
        __syncthreads();
        if (t < SCAN_BLKS) soff[t] += v;
        __syncthreads();
    }

    int p = blockIdx.x * blockDim.x + t;
    if (p >= n) return;
    float px = pos[3 * p], py = pos[3 * p + 1], pz = pos[3 * p + 2];
    int k = bin_key3(px, py, pz);
    int chunk = k >> 10;
    uint32_t base = (chunk > 0) ? soff[chunk - 1] : 0u;
    uint32_t slot = base + atomicAdd(&cursor[k], 1u);
    sortedPts[slot] = make_float4(px, py, pz, __uint_as_float((uint32_t)p));
}

// ---------- main: 16 cell-gathers per point, plain loop, <=64 VGPR ----------
__device__ __forceinline__ void consume_cell(const uint4& v0, const uint4& v1, const uint4& v2,
                                             __half2 wxh, float w, float* acc)
{
    __half2 t; float2 f;
    t = __hfma2(wxh, u2h2(v1.z), u2h2(v0.x)); f = __half22float2(t);
    acc[0] = fmaf(w, f.x, acc[0]); acc[1] = fmaf(w, f.y, acc[1]);
    t = __hfma2(wxh, u2h2(v1.w), u2h2(v0.y)); f = __half22float2(t);
    acc[2] = fmaf(w, f.x, acc[2]); acc[3] = fmaf(w, f.y, acc[3]);
    t = __hfma2(wxh, u2h2(v2.x), u2h2(v0.z)); f = __half22float2(t);
    acc[4] = fmaf(w, f.x, acc[4]); acc[5] = fmaf(w, f.y, acc[5]);
    t = __hfma2(wxh, u2h2(v2.y), u2h2(v0.w)); f = __half22float2(t);
    acc[6] = fmaf(w, f.x, acc[6]); acc[7] = fmaf(w, f.y, acc[7]);
    t = __hfma2(wxh, u2h2(v2.z), u2h2(v1.x)); f = __half22float2(t);
    acc[8] = fmaf(w, f.x, acc[8]); acc[9] = fmaf(w, f.y, acc[9]);
    t = __hfma2(wxh, u2h2(v2.w), u2h2(v1.y)); f = __half22float2(t);
    acc[10] = fmaf(w, f.x, acc[10]); acc[11] = fmaf(w, f.y, acc[11]);
}

__global__ __launch_bounds__(256, 8)
void vapl_grid_sorted_kernel(const float4* __restrict__ sortedPts,
                             const uint32_t* __restrict__ exdx,
                             float* __restrict__ out,   // [N*4] then [N*7], f32
                             int n)
{
    int bid = blockIdx.x;
    int nb  = gridDim.x;
    int b2  = ((nb & 7) == 0) ? ((bid & 7) * (nb >> 3) + (bid >> 3)) : bid;
    int s = b2 * (int)blockDim.x + (int)threadIdx.x;
    if (s >= n) return;

    float4 pt = sortedPts[s];
    int p = (int)__float_as_uint(pt.w);

    float x = ((pt.x + 10.0f) / 20.0f) * 128.0f;
    float y = ((pt.y + 10.0f) / 20.0f) * 128.0f;
    float z = ((pt.z + 10.0f) / 20.0f) * 128.0f;

    float fx = floorf(x), fy = floorf(y), fz = floorf(z);
    int ix = (int)fx, iy = (int)fy, iz = (int)fz;
    float wx = x - fx, wy = y - fy, wz = z - fz;

    float ay[4] = {1.0f - wy, 1.0f, 1.0f, wy};
    float az[4] = {1.0f - wz, 1.0f, 1.0f, wz};
    __half2 wxh = __float2half2_rn(wx);

    int bx = ix + 1, by = iy + 1, bz = iz + 1;

    float acc[12] = {0.f,0.f,0.f,0.f,0.f,0.f,0.f,0.f,0.f,0.f,0.f,0.f};

#pragma unroll
    for (int k = 0; k < 4; ++k) {
        float azk = az[k];
        const uint32_t* rowb = exdx +
            (((size_t)(bz + k) * YD + (size_t)by) * XD + (size_t)(bx - 1)) * RECU;
#pragma unroll
        for (int j = 0; j < 4; ++j) {
            const uint32_t* r = rowb + (size_t)j * (XD * RECU);
            float w = ay[j] * azk;
            uint4 v0 = *(const uint4*)(r);
            uint4 v1 = *(const uint4*)(r + 4);
            uint4 v2 = *(const uint4*)(r + 8);
            consume_cell(v0, v1, v2, wxh, w, acc);
        }
    }

    float m0 = sigmoidf_(acc[0]) * 20.0f - 10.0f;
    float m1 = sigmoidf_(acc[1]) * 20.0f - 10.0f;
    float m2 = sigmoidf_(acc[2]) * 20.0f - 10.0f;
    float var = fmaxf(acc[3], 0.0f) + log1pf(expf(-fabsf(acc[3])));

    float sharp = expf(acc[4]);
    float nrm = fmaxf(sqrtf(acc[5]*acc[5] + acc[6]*acc[6] + acc[7]*acc[7]), 1e-12f);
    float a0 = acc[5] / nrm, a1 = acc[6] / nrm, a2 = acc[7] / nrm;
    float amp0 = sigmoidf_(acc[8]);
    float amp1 = sigmoidf_(acc[9]);
    float amp2 = sigmoidf_(acc[10]);

    *(float4*)(out + (size_t)p * 4) = make_float4(m0, m1, m2, var);

    float* ov = out + (size_t)n * 4 + (size_t)p * 7;
    ov[0] = sharp;
    ov[1] = a0;
    ov[2] = a1;
    ov[3] = a2;
    ov[4] = amp0;
    ov[5] = amp1;
    ov[6] = amp2;
}

// ---------- fallback (ws too small): round-2 two-table kernel ----------
__global__ __launch_bounds__(256)
void vapl_grid_kernel(const float* __restrict__ pos,
                      const float4* __restrict__ gauss,
                      const float4* __restrict__ vmf,
                      float* __restrict__ out,
                      int n)
{
    int p = blockIdx.x * blockDim.x + threadIdx.x;
    if (p >= n) return;

    float px = pos[3 * p + 0];
    float py = pos[3 * p + 1];
    float pz = pos[3 * p + 2];

    float x = ((px + 10.0f) / 20.0f) * 128.0f;
    float y = ((py + 10.0f) / 20.0f) * 128.0f;
    float z = ((pz + 10.0f) / 20.0f) * 128.0f;

    float fx = floorf(x), fy = floorf(y), fz = floorf(z);
    int ix = (int)fx, iy = (int)fy, iz = (int)fz;
    float wx = x - fx, wy = y - fy, wz = z - fz;

    float ax[4] = {1.0f - wx, 1.0f, 1.0f, wx};
    float ay[4] = {1.0f - wy, 1.0f, 1.0f, wy};
    float az[4] = {1.0f - wz, 1.0f, 1.0f, wz};

    uint32_t hx[4], hy[4], hz[4];
#pragma unroll
    for (int i = 0; i < 4; ++i) {
        hx[i] = (uint32_t)(ix - 1 + i);
        hy[i] = (uint32_t)(iy - 1 + i) * P2;
        hz[i] = (uint32_t)(iz - 1 + i) * P3;
    }

    float tg0 = 0.f, tg1 = 0.f, tg2 = 0.f, tg3 = 0.f;
    float tv0 = 0.f, tv1 = 0.f, tv2 = 0.f, tv3 = 0.f;
    float tv4 = 0.f, tv5 = 0.f, tv6 = 0.f, tv7 = 0.f;

    for (int k = 0; k < 4; ++k) {
        for (int j = 0; j < 4; ++j) {
            uint32_t hyz = hy[j] ^ hz[k];
            float wyz = ay[j] * az[k];
#pragma unroll
            for (int i = 0; i < 4; ++i) {
                uint32_t h = (hx[i] ^ hyz) & TABLE_MASK;
                float w = ax[i] * wyz;
                float4 g  = gauss[h];
                float4 v0 = vmf[(size_t)2 * h];
                float4 v1 = vmf[(size_t)2 * h + 1];
                tg0 = fmaf(w, g.x,  tg0);
                tg1 = fmaf(w, g.y,  tg1);
                tg2 = fmaf(w, g.z,  tg2);
                tg3 = fmaf(w, g.w,  tg3);
                tv0 = fmaf(w, v0.x, tv0);
                tv1 = fmaf(w, v0.y, tv1);
                tv2 = fmaf(w, v0.z, tv2);
                tv3 = fmaf(w, v0.w, tv3);
                tv4 = fmaf(w, v1.x, tv4);
                tv5 = fmaf(w, v1.y, tv5);
                tv6 = fmaf(w, v1.z, tv6);
                tv7 = fmaf(w, v1.w, tv7);
            }
        }
    }

    float m0 = sigmoidf_(tg0) * 20.0f - 10.0f;
    float m1 = sigmoidf_(tg1) * 20.0f - 10.0f;
    float m2 = sigmoidf_(tg2) * 20.0f - 10.0f;
    float var = fmaxf(tg3, 0.0f) + log1pf(expf(-fabsf(tg3)));

    float sharp = expf(tv0);
    float nrm = fmaxf(sqrtf(tv1 * tv1 + tv2 * tv2 + tv3 * tv3), 1e-12f);
    float a0 = tv1 / nrm, a1 = tv2 / nrm, a2 = tv3 / nrm;
    float amp0 = sigmoidf_(tv4);
    float amp1 = sigmoidf_(tv5);
    float amp2 = sigmoidf_(tv6);

    float* og = out + (size_t)p * 4;
    og[0] = m0;
    og[1] = m1;
    og[2] = m2;
    og[3] = var;

    float* ov = out + (size_t)n * 4 + (size_t)p * 7;
    ov[0] = sharp;
    ov[1] = a0;
    ov[2] = a1;
    ov[3] = a2;
    ov[4] = amp0;
    ov[5] = amp1;
    ov[6] = amp2;
}

extern "C" void kernel_launch(void* const* d_in, const int* in_sizes, int n_in,
                              void* d_out, int out_size, void* d_ws, size_t ws_size,
                              hipStream_t stream) {
    const float*  pos   = (const float*)d_in[0];
    const float4* gauss = (const float4*)d_in[1];
    const float4* vmf   = (const float4*)d_in[2];
    float* out = (float*)d_out;
    int n = in_sizes[0] / 3;   // 1048576

    // d_ws layout
    size_t off = 0;
    char* ws = (char*)d_ws;
    uint32_t* exdx   = (uint32_t*)(ws + off);  off += (size_t)XD * YD * ZD * RECU * 4;  // ~143 MB
    off = (off + 255) & ~(size_t)255;
    uint32_t* hist   = (uint32_t*)(ws + off);  off += (size_t)NB3 * 4;
    uint32_t* cursor = (uint32_t*)(ws + off);  off += (size_t)NB3 * 4;
    uint32_t* sums   = (uint32_t*)(ws + off);  off += 256 * 4;
    off = (off + 255) & ~(size_t)255;
    float4* sortedPts = (float4*)(ws + off);   off += (size_t)n * 16;                   // 16 MB
    const size_t need = off;

    dim3 block(256);
    dim3 grid((n + 255) / 256);

    if (ws_size >= need) {
        (void)hipMemsetAsync(hist, 0, (size_t)NB3 * 4, stream);
        hipLaunchKernelGGL(build_hist_kernel, dim3(BUILD_BLKS + 4096), block, 0, stream,
                           gauss, vmf, exdx, pos, hist, n);
        hipLaunchKernelGGL(scanA_kernel, dim3(SCAN_BLKS), dim3(1024), 0, stream, hist, cursor, sums);
        hipLaunchKernelGGL(scatter_kernel, grid, block, 0, stream, pos, cursor, sums, sortedPts, n);
        hipLaunchKernelGGL(vapl_grid_sorted_kernel, grid, block, 0, stream,
                           sortedPts, exdx, out, n);
    } else {
        hipLaunchKernelGGL(vapl_grid_kernel, grid, block, 0, stream, pos, gauss, vmf, out, n);
    }
}

// Round 18
// 259.083 us; speedup vs baseline: 1.1866x; 1.1866x over previous
//
#include <hip/hip_runtime.h>
#include <hip/hip_fp16.h>
#include <cstdint>

#define TABLE_MASK 0x3FFFFFu   // 2^22 - 1
#define P2 2654435761u
#define P3 805459861u

#define XD 128                  // exdx x-extent (record x = ix in [0,127])
#define YD 132                  // cy in [1,131]
#define ZD 132                  // cz in [1,131]
#define RECU 12                 // 12 uints = 48 B per cell: Ex(6 half2) + Dx(6 half2)
#define NB3 (128 * 128 * 8)     // bins: (iz, iy, ix/16) raster = 131072
#define SCAN_BLKS (NB3 / 1024)  // 128
#define BUILD_BLKS (131 * 66)   // 8646

__device__ __forceinline__ float sigmoidf_(float x) { return 1.0f / (1.0f + expf(-x)); }

__device__ __forceinline__ uint32_t f2h2(float a, float b) {
    __half2 h = __floats2half2_rn(a, b);
    return *reinterpret_cast<uint32_t*>(&h);
}
__device__ __forceinline__ __half2 u2h2(uint32_t u) {
    return *reinterpret_cast<__half2*>(&u);
}

// ---------- sort key: raster (iz, iy, ix/16) ----------
__device__ __forceinline__ int bin_key3(float px, float py, float pz)
{
    float x = ((px + 10.0f) / 20.0f) * 128.0f;
    float y = ((py + 10.0f) / 20.0f) * 128.0f;
    float z = ((pz + 10.0f) / 20.0f) * 128.0f;
    int ix = min(max((int)floorf(x), 0), 127);
    int iy = min(max((int)floorf(y), 0), 127);
    int iz = min(max((int)floorf(z), 0), 127);
    return (((iz << 7) + iy) << 3) + (ix >> 4);
}

// ---------- fused prepass: build exdx volume (48 B records) + histogram ----------
__global__ __launch_bounds__(256)
void build_hist_kernel(const float4* __restrict__ gauss,
                       const float4* __restrict__ vmf,
                       uint32_t* __restrict__ exdx,
                       const float* __restrict__ pos,
                       uint32_t* __restrict__ hist, int n)
{
    if (blockIdx.x >= BUILD_BLKS) {
        int p = (blockIdx.x - BUILD_BLKS) * blockDim.x + threadIdx.x;
        if (p < n) {
            int k = bin_key3(pos[3 * p], pos[3 * p + 1], pos[3 * p + 2]);
            atomicAdd(&hist[k], 1u);
        }
        return;
    }

    __shared__ float sm[2][131][13];
    int bidx = blockIdx.x;              // 131 z * 66 y-pairs
    int yp = bidx % 66;
    int rz = 1 + bidx / 66;             // [1,131]
    int ry0 = 1 + 2 * yp;
    int t = threadIdx.x;

    for (int l = t; l < 262; l += 256) {
        int row = (l >= 131) ? 1 : 0;
        int cell = l - row * 131;
        int ry = ry0 + row;
        if (ry <= 131) {
            int xc = 1 + cell;
            uint32_t ux = (uint32_t)(xc - 2);
            uint32_t uy = (uint32_t)(ry - 2);
            uint32_t uz = (uint32_t)(rz - 2);
            uint32_t h = (ux ^ (uy * P2) ^ (uz * P3)) & TABLE_MASK;
            float4 g  = gauss[h];
            float4 v0 = vmf[(size_t)2 * h];
            float4 v1 = vmf[(size_t)2 * h + 1];
            float* s = sm[row][cell];
            s[0] = g.x;  s[1] = g.y;  s[2]  = g.z;  s[3]  = g.w;
            s[4] = v0.x; s[5] = v0.y; s[6]  = v0.z; s[7]  = v0.w;
            s[8] = v1.x; s[9] = v1.y; s[10] = v1.z; s[11] = v1.w;
        }
    }
    __syncthreads();

    int row = t >> 7;
    int c   = t & 127;
    int ry  = ry0 + row;
    if (ry > 131) return;

    uint32_t rec[12];
#pragma unroll
    for (int m = 0; m < 6; ++m) {
        float e0 = sm[row][c][2*m]   + sm[row][c+1][2*m]   + sm[row][c+2][2*m];
        float e1 = sm[row][c][2*m+1] + sm[row][c+1][2*m+1] + sm[row][c+2][2*m+1];
        float d0 = sm[row][c+3][2*m]   - sm[row][c][2*m];
        float d1 = sm[row][c+3][2*m+1] - sm[row][c][2*m+1];
        rec[m]     = f2h2(e0, e1);
        rec[6 + m] = f2h2(d0, d1);
    }
    size_t o = (((size_t)rz * YD + (size_t)ry) * XD + (size_t)c) * RECU;
    *(uint4*)(exdx + o)     = make_uint4(rec[0], rec[1], rec[2],  rec[3]);
    *(uint4*)(exdx + o + 4) = make_uint4(rec[4], rec[5], rec[6],  rec[7]);
    *(uint4*)(exdx + o + 8) = make_uint4(rec[8], rec[9], rec[10], rec[11]);
}

// ---------- scanA: per-1024-chunk exclusive prefix + chunk sums ----------
__global__ __launch_bounds__(1024)
void scanA_kernel(const uint32_t* __restrict__ hist,
                  uint32_t* __restrict__ cursor,
                  uint32_t* __restrict__ sums)
{
    __shared__ uint32_t buf[1024];
    int t = threadIdx.x;
    int base = blockIdx.x * 1024;
    uint32_t v = hist[base + t];
    buf[t] = v;
    __syncthreads();
    for (int off = 1; off < 1024; off <<= 1) {
        uint32_t x = (t >= off) ? buf[t - off] : 0u;
        __syncthreads();
        buf[t] += x;
        __syncthreads();
    }
    cursor[base + t] = buf[t] - v;
    if (t == 1023) sums[blockIdx.x] = buf[t];
}

// ---------- scatter: redundant in-block scan of 128 chunk sums, then place ----------
__global__ __launch_bounds__(256)
void scatter_kernel(const float* __restrict__ pos,
                    uint32_t* __restrict__ cursor,
                    const uint32_t* __restrict__ sums,
                    float4* __restrict__ sortedPts, int n)
{
    __shared__ uint32_t soff[SCAN_BLKS];
    int t = threadIdx.x;
    if (t < SCAN_BLKS) soff[t] = sums[t];
    __syncthreads();
    for (int off = 1; off < SCAN_BLKS; off <<= 1) {
        uint32_t v = 0;
        if (t < SCAN_BLKS && t >= off) v = soff[t - off];
        __syncthreads();
        if (t < SCAN_BLKS) soff[t] += v;
        __syncthreads();
    }

    int p = blockIdx.x * blockDim.x + t;
    if (p >= n) return;
    float px = pos[3 * p], py = pos[3 * p + 1], pz = pos[3 * p + 2];
    int k = bin_key3(px, py, pz);
    int chunk = k >> 10;
    uint32_t base = (chunk > 0) ? soff[chunk - 1] : 0u;
    uint32_t slot = base + atomicAdd(&cursor[k], 1u);
    sortedPts[slot] = make_float4(px, py, pz, __uint_as_float((uint32_t)p));
}

// ---------- main: 16 cell-gathers per point, plain loop, <=64 VGPR ----------
__device__ __forceinline__ void consume_cell(const uint4& v0, const uint4& v1, const uint4& v2,
                                             __half2 wxh, float w, float* acc)
{
    __half2 t; float2 f;
    t = __hfma2(wxh, u2h2(v1.z), u2h2(v0.x)); f = __half22float2(t);
    acc[0] = fmaf(w, f.x, acc[0]); acc[1] = fmaf(w, f.y, acc[1]);
    t = __hfma2(wxh, u2h2(v1.w), u2h2(v0.y)); f = __half22float2(t);
    acc[2] = fmaf(w, f.x, acc[2]); acc[3] = fmaf(w, f.y, acc[3]);
    t = __hfma2(wxh, u2h2(v2.x), u2h2(v0.z)); f = __half22float2(t);
    acc[4] = fmaf(w, f.x, acc[4]); acc[5] = fmaf(w, f.y, acc[5]);
    t = __hfma2(wxh, u2h2(v2.y), u2h2(v0.w)); f = __half22float2(t);
    acc[6] = fmaf(w, f.x, acc[6]); acc[7] = fmaf(w, f.y, acc[7]);
    t = __hfma2(wxh, u2h2(v2.z), u2h2(v1.x)); f = __half22float2(t);
    acc[8] = fmaf(w, f.x, acc[8]); acc[9] = fmaf(w, f.y, acc[9]);
    t = __hfma2(wxh, u2h2(v2.w), u2h2(v1.y)); f = __half22float2(t);
    acc[10] = fmaf(w, f.x, acc[10]); acc[11] = fmaf(w, f.y, acc[11]);
}

__global__ __launch_bounds__(256, 8)
void vapl_grid_sorted_kernel(const float4* __restrict__ sortedPts,
                             const uint32_t* __restrict__ exdx,
                             float* __restrict__ out,   // [N*4] then [N*7], f32
                             int n)
{
    int bid = blockIdx.x;
    int nb  = gridDim.x;
    int b2  = ((nb & 7) == 0) ? ((bid & 7) * (nb >> 3) + (bid >> 3)) : bid;
    int s = b2 * (int)blockDim.x + (int)threadIdx.x;
    if (s >= n) return;

    float4 pt = sortedPts[s];
    int p = (int)__float_as_uint(pt.w);

    float x = ((pt.x + 10.0f) / 20.0f) * 128.0f;
    float y = ((pt.y + 10.0f) / 20.0f) * 128.0f;
    float z = ((pt.z + 10.0f) / 20.0f) * 128.0f;

    float fx = floorf(x), fy = floorf(y), fz = floorf(z);
    int ix = (int)fx, iy = (int)fy, iz = (int)fz;
    float wx = x - fx, wy = y - fy, wz = z - fz;

    float ay[4] = {1.0f - wy, 1.0f, 1.0f, wy};
    float az[4] = {1.0f - wz, 1.0f, 1.0f, wz};
    __half2 wxh = __float2half2_rn(wx);

    int bx = ix + 1, by = iy + 1, bz = iz + 1;

    float acc[12] = {0.f,0.f,0.f,0.f,0.f,0.f,0.f,0.f,0.f,0.f,0.f,0.f};

#pragma unroll
    for (int k = 0; k < 4; ++k) {
        float azk = az[k];
        const uint32_t* rowb = exdx +
            (((size_t)(bz + k) * YD + (size_t)by) * XD + (size_t)(bx - 1)) * RECU;
#pragma unroll
        for (int j = 0; j < 4; ++j) {
            const uint32_t* r = rowb + (size_t)j * (XD * RECU);
            float w = ay[j] * azk;
            uint4 v0 = *(const uint4*)(r);
            uint4 v1 = *(const uint4*)(r + 4);
            uint4 v2 = *(const uint4*)(r + 8);
            consume_cell(v0, v1, v2, wxh, w, acc);
        }
    }

    float m0 = sigmoidf_(acc[0]) * 20.0f - 10.0f;
    float m1 = sigmoidf_(acc[1]) * 20.0f - 10.0f;
    float m2 = sigmoidf_(acc[2]) * 20.0f - 10.0f;
    float var = fmaxf(acc[3], 0.0f) + log1pf(expf(-fabsf(acc[3])));

    float sharp = expf(acc[4]);
    float nrm = fmaxf(sqrtf(acc[5]*acc[5] + acc[6]*acc[6] + acc[7]*acc[7]), 1e-12f);
    float a0 = acc[5] / nrm, a1 = acc[6] / nrm, a2 = acc[7] / nrm;
    float amp0 = sigmoidf_(acc[8]);
    float amp1 = sigmoidf_(acc[9]);
    float amp2 = sigmoidf_(acc[10]);

    *(float4*)(out + (size_t)p * 4) = make_float4(m0, m1, m2, var);

    float* ov = out + (size_t)n * 4 + (size_t)p * 7;
    ov[0] = sharp;
    ov[1] = a0;
    ov[2] = a1;
    ov[3] = a2;
    ov[4] = amp0;
    ov[5] = amp1;
    ov[6] = amp2;
}

// ---------- fallback (ws too small): round-2 two-table kernel ----------
__global__ __launch_bounds__(256)
void vapl_grid_kernel(const float* __restrict__ pos,
                      const float4* __restrict__ gauss,
                      const float4* __restrict__ vmf,
                      float* __restrict__ out,
                      int n)
{
    int p = blockIdx.x * blockDim.x + threadIdx.x;
    if (p >= n) return;

    float px = pos[3 * p + 0];
    float py = pos[3 * p + 1];
    float pz = pos[3 * p + 2];

    float x = ((px + 10.0f) / 20.0f) * 128.0f;
    float y = ((py + 10.0f) / 20.0f) * 128.0f;
    float z = ((pz + 10.0f) / 20.0f) * 128.0f;

    float fx = floorf(x), fy = floorf(y), fz = floorf(z);
    int ix = (int)fx, iy = (int)fy, iz = (int)fz;
    float wx = x - fx, wy = y - fy, wz = z - fz;

    float ax[4] = {1.0f - wx, 1.0f, 1.0f, wx};
    float ay[4] = {1.0f - wy, 1.0f, 1.0f, wy};
    float az[4] = {1.0f - wz, 1.0f, 1.0f, wz};

    uint32_t hx[4], hy[4], hz[4];
#pragma unroll
    for (int i = 0; i < 4; ++i) {
        hx[i] = (uint32_t)(ix - 1 + i);
        hy[i] = (uint32_t)(iy - 1 + i) * P2;
        hz[i] = (uint32_t)(iz - 1 + i) * P3;
    }

    float tg0 = 0.f, tg1 = 0.f, tg2 = 0.f, tg3 = 0.f;
    float tv0 = 0.f, tv1 = 0.f, tv2 = 0.f, tv3 = 0.f;
    float tv4 = 0.f, tv5 = 0.f, tv6 = 0.f, tv7 = 0.f;

    for (int k = 0; k < 4; ++k) {
        for (int j = 0; j < 4; ++j) {
            uint32_t hyz = hy[j] ^ hz[k];
            float wyz = ay[j] * az[k];
#pragma unroll
            for (int i = 0; i < 4; ++i) {
                uint32_t h = (hx[i] ^ hyz) & TABLE_MASK;
                float w = ax[i] * wyz;
                float4 g  = gauss[h];
                float4 v0 = vmf[(size_t)2 * h];
                float4 v1 = vmf[(size_t)2 * h + 1];
                tg0 = fmaf(w, g.x,  tg0);
                tg1 = fmaf(w, g.y,  tg1);
                tg2 = fmaf(w, g.z,  tg2);
                tg3 = fmaf(w, g.w,  tg3);
                tv0 = fmaf(w, v0.x, tv0);
                tv1 = fmaf(w, v0.y, tv1);
                tv2 = fmaf(w, v0.z, tv2);
                tv3 = fmaf(w, v0.w, tv3);
                tv4 = fmaf(w, v1.x, tv4);
                tv5 = fmaf(w, v1.y, tv5);
                tv6 = fmaf(w, v1.z, tv6);
                tv7 = fmaf(w, v1.w, tv7);
            }
        }
    }

    float m0 = sigmoidf_(tg0) * 20.0f - 10.0f;
    float m1 = sigmoidf_(tg1) * 20.0f - 10.0f;
    float m2 = sigmoidf_(tg2) * 20.0f - 10.0f;
    float var = fmaxf(tg3, 0.0f) + log1pf(expf(-fabsf(tg3)));

    float sharp = expf(tv0);
    float nrm = fmaxf(sqrtf(tv1 * tv1 + tv2 * tv2 + tv3 * tv3), 1e-12f);
    float a0 = tv1 / nrm, a1 = tv2 / nrm, a2 = tv3 / nrm;
    float amp0 = sigmoidf_(tv4);
    float amp1 = sigmoidf_(tv5);
    float amp2 = sigmoidf_(tv6);

    float* og = out + (size_t)p * 4;
    og[0] = m0;
    og[1] = m1;
    og[2] = m2;
    og[3] = var;

    float* ov = out + (size_t)n * 4 + (size_t)p * 7;
    ov[0] = sharp;
    ov[1] = a0;
    ov[2] = a1;
    ov[3] = a2;
    ov[4] = amp0;
    ov[5] = amp1;
    ov[6] = amp2;
}

extern "C" void kernel_launch(void* const* d_in, const int* in_sizes, int n_in,
                              void* d_out, int out_size, void* d_ws, size_t ws_size,
                              hipStream_t stream) {
    const float*  pos   = (const float*)d_in[0];
    const float4* gauss = (const float4*)d_in[1];
    const float4* vmf   = (const float4*)d_in[2];
    float* out = (float*)d_out;
    int n = in_sizes[0] / 3;   // 1048576

    // d_ws layout
    size_t off = 0;
    char* ws = (char*)d_ws;
    uint32_t* exdx   = (uint32_t*)(ws + off);  off += (size_t)XD * YD * ZD * RECU * 4;  // ~107 MB
    off = (off + 255) & ~(size_t)255;
    uint32_t* hist   = (uint32_t*)(ws + off);  off += (size_t)NB3 * 4;
    uint32_t* cursor = (uint32_t*)(ws + off);  off += (size_t)NB3 * 4;
    uint32_t* sums   = (uint32_t*)(ws + off);  off += 256 * 4;
    off = (off + 255) & ~(size_t)255;
    float4* sortedPts = (float4*)(ws + off);   off += (size_t)n * 16;                   // 16 MB
    const size_t need = off;

    dim3 block(256);
    dim3 grid((n + 255) / 256);

    if (ws_size >= need) {
        (void)hipMemsetAsync(hist, 0, (size_t)NB3 * 4, stream);
        hipLaunchKernelGGL(build_hist_kernel, dim3(BUILD_BLKS + 4096), block, 0, stream,
                           gauss, vmf, exdx, pos, hist, n);
        hipLaunchKernelGGL(scanA_kernel, dim3(SCAN_BLKS), dim3(1024), 0, stream, hist, cursor, sums);
        hipLaunchKernelGGL(scatter_kernel, grid, block, 0, stream, pos, cursor, sums, sortedPts, n);
        hipLaunchKernelGGL(vapl_grid_sorted_kernel, grid, block, 0, stream,
                           sortedPts, exdx, out, n);
    } else {
        hipLaunchKernelGGL(vapl_grid_kernel, grid, block, 0, stream, pos, gauss, vmf, out, n);
    }
}